// Round 1
// baseline (55896.997 us; speedup 1.0000x reference)
//
#include <hip/hip_runtime.h>
#include <math.h>

// Problem constants
#define Bsz 32
#define Tt  512
#define Isz 256
#define Hsz 512
#define G3  1536
#define Osz 128

// Recurrence kernel config
#define NBLK 256
#define TPB  256
#define FLAG_STRIDE 16   // ints (64B) between flags

// ---------------- init flags ----------------
__global__ void init_flags(int* flags) {
    int i = threadIdx.x + blockIdx.x * blockDim.x;
    int n = NBLK * FLAG_STRIDE;
    for (; i < n; i += blockDim.x * gridDim.x) flags[i] = 0;
}

// ---------------- grid barrier ----------------
__device__ __forceinline__ void gbar(int* flags, int nb, int tid, int gen) {
    __threadfence();
    __syncthreads();
    if (tid == 0) {
        __hip_atomic_store(&flags[nb * FLAG_STRIDE], gen, __ATOMIC_RELEASE,
                           __HIP_MEMORY_SCOPE_AGENT);
    }
    if (tid < 64) {
        int i0 = tid * 4;
        for (;;) {
            int m0 = __hip_atomic_load(&flags[(i0 + 0) * FLAG_STRIDE], __ATOMIC_ACQUIRE, __HIP_MEMORY_SCOPE_AGENT);
            int m1 = __hip_atomic_load(&flags[(i0 + 1) * FLAG_STRIDE], __ATOMIC_ACQUIRE, __HIP_MEMORY_SCOPE_AGENT);
            int m2 = __hip_atomic_load(&flags[(i0 + 2) * FLAG_STRIDE], __ATOMIC_ACQUIRE, __HIP_MEMORY_SCOPE_AGENT);
            int m3 = __hip_atomic_load(&flags[(i0 + 3) * FLAG_STRIDE], __ATOMIC_ACQUIRE, __HIP_MEMORY_SCOPE_AGENT);
            int ok = (m0 >= gen) && (m1 >= gen) && (m2 >= gen) && (m3 >= gen);
            if (__all(ok)) break;
            __builtin_amdgcn_s_sleep(2);
        }
    }
    __syncthreads();
}

__device__ __forceinline__ float sigf(float x) { return 1.0f / (1.0f + expf(-x)); }

// ---------------- persistent GRU recurrence (one layer) ----------------
// Block nb owns output columns j0=2*nb, j0+1. W_hh rows for those columns are
// held in registers for the whole kernel. h (fp32, [B,H]) is double-buffered
// in global ws; staged into LDS each step with agent-scope loads (L1 bypass).
__global__ void __launch_bounds__(TPB, 1) gru_rec(
    const float* __restrict__ xp,    // [B*T, 3H] (includes b_ih)
    const float* __restrict__ Whh,   // [3H, H]
    const float* __restrict__ bhh,   // [3H]
    float* __restrict__ hall,        // [B*T, H]
    float* __restrict__ hbuf,        // [2][B*H]
    int* __restrict__ flags,
    float* __restrict__ hid_out,     // [B*H] slice of d_out hidden for this layer
    int gen_base)
{
    const int tid = threadIdx.x;
    const int nb  = blockIdx.x;
    const int kc  = tid & 15;          // k-chunk (16 chunks of 32)
    const int jl  = (tid >> 4) & 1;    // which of the 2 owned columns
    const int bq  = tid >> 5;          // batch quad 0..7
    const int j0  = nb * 2;
    const int j   = j0 + jl;

    __shared__ float hsh[Bsz * Hsz];   // 64KB; also reused for W staging

    // ---- stage W_hh rows (6 rows x 512) into LDS, then registers ----
    for (int i = 0; i < 12; ++i) {
        int idx = i * TPB + tid;       // 0..3071
        int rl  = idx >> 9;            // row-local 0..5
        int col = idx & 511;
        int grow = (rl >> 1) * Hsz + j0 + (rl & 1);
        hsh[idx] = Whh[(size_t)grow * Hsz + col];
    }
    __syncthreads();
    float4 wreg[3][8];
    #pragma unroll
    for (int g = 0; g < 3; ++g) {
        int rl = g * 2 + jl;
        #pragma unroll
        for (int q = 0; q < 8; ++q)
            wreg[g][q] = *reinterpret_cast<const float4*>(&hsh[rl * Hsz + kc * 32 + q * 4]);
    }
    __syncthreads();

    const float bh0 = bhh[0 * Hsz + j];
    const float bh1 = bhh[1 * Hsz + j];
    const float bh2 = bhh[2 * Hsz + j];

    // ---- zero h0 into hbuf[0] ----
    if (kc == 0) {
        #pragma unroll
        for (int bi = 0; bi < 4; ++bi) {
            int b = bq * 4 + bi;
            __hip_atomic_store(&hbuf[b * Hsz + j], 0.0f, __ATOMIC_RELAXED,
                               __HIP_MEMORY_SCOPE_AGENT);
        }
    }
    gbar(flags, nb, tid, gen_base + 1);

    for (int t = 0; t < Tt; ++t) {
        const float* hsrc = hbuf + (size_t)(t & 1) * (Bsz * Hsz);
        float*       hdst = hbuf + (size_t)((t + 1) & 1) * (Bsz * Hsz);

        // prefetch xp for the owner lanes (hidden under staging+compute)
        float xr[4], xz[4], xn[4];
        if (kc == 0) {
            #pragma unroll
            for (int bi = 0; bi < 4; ++bi) {
                int b = bq * 4 + bi;
                const float* p = xp + (size_t)(b * Tt + t) * G3;
                xr[bi] = p[j];
                xz[bi] = p[Hsz + j];
                xn[bi] = p[2 * Hsz + j];
            }
        }

        // stage h(t) into LDS (agent loads -> always fresh from L2)
        #pragma unroll 8
        for (int i = 0; i < 64; ++i) {
            int idx = i * TPB + tid;
            hsh[idx] = __hip_atomic_load(&hsrc[idx], __ATOMIC_RELAXED,
                                         __HIP_MEMORY_SCOPE_AGENT);
        }
        __syncthreads();

        // partial dot products: gates r,z,n for column j, 4 batches, k-chunk kc*32..+32
        float acc[3][4];
        #pragma unroll
        for (int g = 0; g < 3; ++g)
            #pragma unroll
            for (int bi = 0; bi < 4; ++bi) acc[g][bi] = 0.0f;

        #pragma unroll
        for (int bi = 0; bi < 4; ++bi) {
            int b = bq * 4 + bi;
            const float4* hp = reinterpret_cast<const float4*>(&hsh[b * Hsz + kc * 32]);
            float4 h4[8];
            #pragma unroll
            for (int q = 0; q < 8; ++q) h4[q] = hp[q];
            #pragma unroll
            for (int g = 0; g < 3; ++g) {
                float s = 0.0f;
                #pragma unroll
                for (int q = 0; q < 8; ++q) {
                    s = fmaf(wreg[g][q].x, h4[q].x, s);
                    s = fmaf(wreg[g][q].y, h4[q].y, s);
                    s = fmaf(wreg[g][q].z, h4[q].z, s);
                    s = fmaf(wreg[g][q].w, h4[q].w, s);
                }
                acc[g][bi] = s;
            }
        }

        // reduce across the 16 kc lanes (low 4 lane bits)
        #pragma unroll
        for (int off = 1; off < 16; off <<= 1) {
            #pragma unroll
            for (int g = 0; g < 3; ++g)
                #pragma unroll
                for (int bi = 0; bi < 4; ++bi)
                    acc[g][bi] += __shfl_xor(acc[g][bi], off, 64);
        }

        if (kc == 0) {
            #pragma unroll
            for (int bi = 0; bi < 4; ++bi) {
                int b = bq * 4 + bi;
                float ghr = acc[0][bi] + bh0;
                float ghz = acc[1][bi] + bh1;
                float ghn = acc[2][bi] + bh2;
                float r = sigf(xr[bi] + ghr);
                float z = sigf(xz[bi] + ghz);
                float n = tanhf(xn[bi] + r * ghn);
                float ho = hsh[b * Hsz + j];
                float hv = (1.0f - z) * n + z * ho;
                __hip_atomic_store(&hdst[b * Hsz + j], hv, __ATOMIC_RELAXED,
                                   __HIP_MEMORY_SCOPE_AGENT);
                hall[(size_t)(b * Tt + t) * Hsz + j] = hv;
                if (t == Tt - 1) hid_out[b * Hsz + j] = hv;
            }
        }

        gbar(flags, nb, tid, gen_base + t + 2);
    }
}

// ---------------- fp32 GEMM: C[M,N] = A[M,K] * W[N,K]^T + bias[N] ----------------
#define GM 64
#define GN 64
#define GK 16
__global__ void __launch_bounds__(256) gemm_nt_bias(
    const float* __restrict__ A, const float* __restrict__ W,
    const float* __restrict__ bias, float* __restrict__ C,
    int M, int N, int K)
{
    __shared__ float As[GK][GM];
    __shared__ float Bs[GK][GN];
    const int tid = threadIdx.x;
    const int n0 = blockIdx.x * GN;
    const int m0 = blockIdx.y * GM;
    const int tn = tid & 15;
    const int tm = tid >> 4;
    const int lrow = tid >> 2;   // 0..63
    const int lkq  = tid & 3;    // 0..3

    float acc[4][4];
    #pragma unroll
    for (int i = 0; i < 4; ++i)
        #pragma unroll
        for (int jj = 0; jj < 4; ++jj) acc[i][jj] = 0.0f;

    for (int k0 = 0; k0 < K; k0 += GK) {
        float4 av = *reinterpret_cast<const float4*>(&A[(size_t)(m0 + lrow) * K + k0 + lkq * 4]);
        float4 wv = *reinterpret_cast<const float4*>(&W[(size_t)(n0 + lrow) * K + k0 + lkq * 4]);
        __syncthreads();
        As[lkq * 4 + 0][lrow] = av.x; As[lkq * 4 + 1][lrow] = av.y;
        As[lkq * 4 + 2][lrow] = av.z; As[lkq * 4 + 3][lrow] = av.w;
        Bs[lkq * 4 + 0][lrow] = wv.x; Bs[lkq * 4 + 1][lrow] = wv.y;
        Bs[lkq * 4 + 2][lrow] = wv.z; Bs[lkq * 4 + 3][lrow] = wv.w;
        __syncthreads();
        #pragma unroll
        for (int k = 0; k < GK; ++k) {
            float4 a4 = *reinterpret_cast<const float4*>(&As[k][tm * 4]);
            float4 b4 = *reinterpret_cast<const float4*>(&Bs[k][tn * 4]);
            acc[0][0] = fmaf(a4.x, b4.x, acc[0][0]); acc[0][1] = fmaf(a4.x, b4.y, acc[0][1]);
            acc[0][2] = fmaf(a4.x, b4.z, acc[0][2]); acc[0][3] = fmaf(a4.x, b4.w, acc[0][3]);
            acc[1][0] = fmaf(a4.y, b4.x, acc[1][0]); acc[1][1] = fmaf(a4.y, b4.y, acc[1][1]);
            acc[1][2] = fmaf(a4.y, b4.z, acc[1][2]); acc[1][3] = fmaf(a4.y, b4.w, acc[1][3]);
            acc[2][0] = fmaf(a4.z, b4.x, acc[2][0]); acc[2][1] = fmaf(a4.z, b4.y, acc[2][1]);
            acc[2][2] = fmaf(a4.z, b4.z, acc[2][2]); acc[2][3] = fmaf(a4.z, b4.w, acc[2][3]);
            acc[3][0] = fmaf(a4.w, b4.x, acc[3][0]); acc[3][1] = fmaf(a4.w, b4.y, acc[3][1]);
            acc[3][2] = fmaf(a4.w, b4.z, acc[3][2]); acc[3][3] = fmaf(a4.w, b4.w, acc[3][3]);
        }
    }

    float4 bb = *reinterpret_cast<const float4*>(&bias[n0 + tn * 4]);
    #pragma unroll
    for (int i = 0; i < 4; ++i) {
        int m = m0 + tm * 4 + i;
        float4 o;
        o.x = acc[i][0] + bb.x; o.y = acc[i][1] + bb.y;
        o.z = acc[i][2] + bb.z; o.w = acc[i][3] + bb.w;
        *reinterpret_cast<float4*>(&C[(size_t)m * N + n0 + tn * 4]) = o;
    }
}

// ---------------- host launcher ----------------
extern "C" void kernel_launch(void* const* d_in, const int* in_sizes, int n_in,
                              void* d_out, int out_size, void* d_ws, size_t ws_size,
                              hipStream_t stream) {
    (void)in_sizes; (void)n_in; (void)out_size; (void)ws_size;
    const float* x    = (const float*)d_in[0];
    const float* Wih0 = (const float*)d_in[1];
    const float* Whh0 = (const float*)d_in[2];
    const float* bih0 = (const float*)d_in[3];
    const float* bhh0 = (const float*)d_in[4];
    const float* Wih1 = (const float*)d_in[5];
    const float* Whh1 = (const float*)d_in[6];
    const float* bih1 = (const float*)d_in[7];
    const float* bhh1 = (const float*)d_in[8];
    const float* fcW  = (const float*)d_in[9];
    const float* fcb  = (const float*)d_in[10];

    float* out = (float*)d_out;                       // [B,T,O]
    float* hid = out + (size_t)Bsz * Tt * Osz;        // [L,B,H]

    char* ws = (char*)d_ws;
    const size_t xp_off    = 0;                               // [16384,1536] f32 = 100663296 B
    const size_t hall_off  = xp_off + (size_t)Bsz * Tt * G3 * 4;      // +100663296
    const size_t hbuf_off  = hall_off + (size_t)Bsz * Tt * Hsz * 4;   // +33554432
    const size_t flags_off = hbuf_off + (size_t)2 * Bsz * Hsz * 4;    // +131072
    float* xp    = (float*)(ws + xp_off);
    float* hall  = (float*)(ws + hall_off);
    float* hbuf  = (float*)(ws + hbuf_off);
    int*   flags = (int*)  (ws + flags_off);

    hipLaunchKernelGGL(init_flags, dim3(16), dim3(256), 0, stream, flags);

    // layer 0 input projection: xp = x @ Wih0^T + bih0   (M=16384, N=1536, K=256)
    hipLaunchKernelGGL(gemm_nt_bias, dim3(G3 / GN, (Bsz * Tt) / GM), dim3(256), 0, stream,
                       x, Wih0, bih0, xp, Bsz * Tt, G3, Isz);

    // layer 0 recurrence
    hipLaunchKernelGGL(gru_rec, dim3(NBLK), dim3(TPB), 0, stream,
                       xp, Whh0, bhh0, hall, hbuf, flags, hid, 0);

    // layer 1 input projection: xp = hall @ Wih1^T + bih1  (K=512)
    hipLaunchKernelGGL(gemm_nt_bias, dim3(G3 / GN, (Bsz * Tt) / GM), dim3(256), 0, stream,
                       hall, Wih1, bih1, xp, Bsz * Tt, G3, Hsz);

    // layer 1 recurrence (overwrites hall)
    hipLaunchKernelGGL(gru_rec, dim3(NBLK), dim3(TPB), 0, stream,
                       xp, Whh1, bhh1, hall, hbuf, flags, hid + Bsz * Hsz, 513);

    // FC: out = hall @ fcW^T + fcb  (N=128)
    hipLaunchKernelGGL(gemm_nt_bias, dim3(Osz / GN, (Bsz * Tt) / GM), dim3(256), 0, stream,
                       hall, fcW, fcb, out, Bsz * Tt, Osz, Hsz);
}

// Round 2
// 37877.527 us; speedup vs baseline: 1.4757x; 1.4757x over previous
//
#include <hip/hip_runtime.h>
#include <math.h>

// Problem constants
#define Bsz 32
#define Tt  512
#define Isz 256
#define Hsz 512
#define G3  1536
#define Osz 128

// Recurrence kernel config
#define NBLK 256
#define TPB  256
#define FLAG_STRIDE 16   // ints (64B) between flags

// ---------------- init flags ----------------
__global__ void init_flags(int* flags) {
    int i = threadIdx.x + blockIdx.x * blockDim.x;
    int n = NBLK * FLAG_STRIDE;
    for (; i < n; i += blockDim.x * gridDim.x) flags[i] = 0;
}

// ---------------- grid barrier ----------------
// Release: threadfence (agent-scope release -> L2 writeback) + flag store.
// Poll: RELAXED agent-scope loads (no invalidate, no waitcnt serialization).
// Caller issues ONE acquire fence after the barrier before reading shared data.
__device__ __forceinline__ void gbar(int* flags, int nb, int tid, int gen) {
    __threadfence();
    __syncthreads();
    if (tid == 0) {
        __hip_atomic_store(&flags[nb * FLAG_STRIDE], gen, __ATOMIC_RELEASE,
                           __HIP_MEMORY_SCOPE_AGENT);
    }
    if (tid < 64) {
        int i0 = tid * 4;
        for (;;) {
            int m0 = __hip_atomic_load(&flags[(i0 + 0) * FLAG_STRIDE], __ATOMIC_RELAXED, __HIP_MEMORY_SCOPE_AGENT);
            int m1 = __hip_atomic_load(&flags[(i0 + 1) * FLAG_STRIDE], __ATOMIC_RELAXED, __HIP_MEMORY_SCOPE_AGENT);
            int m2 = __hip_atomic_load(&flags[(i0 + 2) * FLAG_STRIDE], __ATOMIC_RELAXED, __HIP_MEMORY_SCOPE_AGENT);
            int m3 = __hip_atomic_load(&flags[(i0 + 3) * FLAG_STRIDE], __ATOMIC_RELAXED, __HIP_MEMORY_SCOPE_AGENT);
            int ok = (m0 >= gen) && (m1 >= gen) && (m2 >= gen) && (m3 >= gen);
            if (__all(ok)) break;
            __builtin_amdgcn_s_sleep(2);
        }
    }
    __syncthreads();
}

__device__ __forceinline__ float sigf(float x) { return 1.0f / (1.0f + expf(-x)); }

// ---------------- persistent GRU recurrence (one layer) ----------------
__global__ void __launch_bounds__(TPB, 1) gru_rec(
    const float* __restrict__ xp,    // [B*T, 3H] (includes b_ih)
    const float* __restrict__ Whh,   // [3H, H]
    const float* __restrict__ bhh,   // [3H]
    float* __restrict__ hall,        // [B*T, H]
    float* __restrict__ hbuf,        // [2][B*H]
    int* __restrict__ flags,
    float* __restrict__ hid_out,     // [B*H] slice of d_out hidden
    int gen_base)
{
    const int tid = threadIdx.x;
    const int nb  = blockIdx.x;
    const int kc  = tid & 15;          // k-chunk selector
    const int jl  = (tid >> 4) & 1;    // which of the 2 owned columns
    const int bq  = tid >> 5;          // batch quad 0..7
    const int j0  = nb * 2;
    const int j   = j0 + jl;

    __shared__ float hsh[Bsz * Hsz];   // 64KB; also reused for W staging

    // ---- stage W_hh rows (6 rows x 512) into LDS, then registers ----
    for (int i = 0; i < 12; ++i) {
        int idx = i * TPB + tid;       // 0..3071
        int rl  = idx >> 9;            // row-local 0..5
        int col = idx & 511;
        int grow = (rl >> 1) * Hsz + j0 + (rl & 1);
        hsh[idx] = Whh[(size_t)grow * Hsz + col];
    }
    __syncthreads();
    float4 wreg[3][8];
    #pragma unroll
    for (int g = 0; g < 3; ++g) {
        int rl = g * 2 + jl;
        #pragma unroll
        for (int q = 0; q < 8; ++q)
            wreg[g][q] = *reinterpret_cast<const float4*>(&hsh[rl * Hsz + q * 64 + kc * 4]);
    }
    __syncthreads();

    const float bh0 = bhh[0 * Hsz + j];
    const float bh1 = bhh[1 * Hsz + j];
    const float bh2 = bhh[2 * Hsz + j];

    // ---- zero h0 into hbuf[0] ----
    if (kc == 0) {
        #pragma unroll
        for (int bi = 0; bi < 4; ++bi) {
            int b = bq * 4 + bi;
            hbuf[b * Hsz + j] = 0.0f;
        }
    }
    gbar(flags, nb, tid, gen_base + 1);

    for (int t = 0; t < Tt; ++t) {
        const float* hsrc = hbuf + (size_t)(t & 1) * (Bsz * Hsz);
        float*       hdst = hbuf + (size_t)((t + 1) & 1) * (Bsz * Hsz);

        // single invalidate: makes other blocks' h(t) stores visible to plain loads
        __builtin_amdgcn_fence(__ATOMIC_ACQUIRE, "agent");

        // xp for the owner lanes (issued early, used after compute)
        float xr[4], xz[4], xn[4];
        if (kc == 0) {
            #pragma unroll
            for (int bi = 0; bi < 4; ++bi) {
                int b = bq * 4 + bi;
                const float* p = xp + (size_t)(b * Tt + t) * G3;
                xr[bi] = p[j];
                xz[bi] = p[Hsz + j];
                xn[bi] = p[2 * Hsz + j];
            }
        }

        // stage h(t) into LDS: 16 pipelined float4 loads per thread
        {
            const float4* hsrc4 = reinterpret_cast<const float4*>(hsrc);
            float4* hsh4 = reinterpret_cast<float4*>(hsh);
            #pragma unroll
            for (int i = 0; i < 16; ++i) {
                int idx4 = i * TPB + tid;
                hsh4[idx4] = hsrc4[idx4];
            }
        }
        __syncthreads();

        // partial dot products: gates r,z,n for column j, 4 batches
        float acc[3][4];
        #pragma unroll
        for (int g = 0; g < 3; ++g)
            #pragma unroll
            for (int bi = 0; bi < 4; ++bi) acc[g][bi] = 0.0f;

        #pragma unroll
        for (int bi = 0; bi < 4; ++bi) {
            int b = bq * 4 + bi;
            const float4* hp = reinterpret_cast<const float4*>(&hsh[b * Hsz]);
            float4 h4[8];
            #pragma unroll
            for (int q = 0; q < 8; ++q) h4[q] = hp[q * 16 + kc];   // consecutive across kc lanes
            #pragma unroll
            for (int g = 0; g < 3; ++g) {
                float s = 0.0f;
                #pragma unroll
                for (int q = 0; q < 8; ++q) {
                    s = fmaf(wreg[g][q].x, h4[q].x, s);
                    s = fmaf(wreg[g][q].y, h4[q].y, s);
                    s = fmaf(wreg[g][q].z, h4[q].z, s);
                    s = fmaf(wreg[g][q].w, h4[q].w, s);
                }
                acc[g][bi] = s;
            }
        }

        // reduce across the 16 kc lanes (low 4 lane bits)
        #pragma unroll
        for (int off = 1; off < 16; off <<= 1) {
            #pragma unroll
            for (int g = 0; g < 3; ++g)
                #pragma unroll
                for (int bi = 0; bi < 4; ++bi)
                    acc[g][bi] += __shfl_xor(acc[g][bi], off, 64);
        }

        if (kc == 0) {
            #pragma unroll
            for (int bi = 0; bi < 4; ++bi) {
                int b = bq * 4 + bi;
                float ghr = acc[0][bi] + bh0;
                float ghz = acc[1][bi] + bh1;
                float ghn = acc[2][bi] + bh2;
                float r = sigf(xr[bi] + ghr);
                float z = sigf(xz[bi] + ghz);
                float n = tanhf(xn[bi] + r * ghn);
                float ho = hsh[b * Hsz + j];
                float hv = (1.0f - z) * n + z * ho;
                hdst[b * Hsz + j] = hv;
                hall[(size_t)(b * Tt + t) * Hsz + j] = hv;
                if (t == Tt - 1) hid_out[b * Hsz + j] = hv;
            }
        }

        gbar(flags, nb, tid, gen_base + t + 2);
    }
}

// ---------------- fp32 GEMM: C[M,N] = A[M,K] * W[N,K]^T + bias[N] ----------------
#define GM 64
#define GN 64
#define GK 16
__global__ void __launch_bounds__(256) gemm_nt_bias(
    const float* __restrict__ A, const float* __restrict__ W,
    const float* __restrict__ bias, float* __restrict__ C,
    int M, int N, int K)
{
    __shared__ float As[GK][GM];
    __shared__ float Bs[GK][GN];
    const int tid = threadIdx.x;
    const int n0 = blockIdx.x * GN;
    const int m0 = blockIdx.y * GM;
    const int tn = tid & 15;
    const int tm = tid >> 4;
    const int lrow = tid >> 2;   // 0..63
    const int lkq  = tid & 3;    // 0..3

    float acc[4][4];
    #pragma unroll
    for (int i = 0; i < 4; ++i)
        #pragma unroll
        for (int jj = 0; jj < 4; ++jj) acc[i][jj] = 0.0f;

    for (int k0 = 0; k0 < K; k0 += GK) {
        float4 av = *reinterpret_cast<const float4*>(&A[(size_t)(m0 + lrow) * K + k0 + lkq * 4]);
        float4 wv = *reinterpret_cast<const float4*>(&W[(size_t)(n0 + lrow) * K + k0 + lkq * 4]);
        __syncthreads();
        As[lkq * 4 + 0][lrow] = av.x; As[lkq * 4 + 1][lrow] = av.y;
        As[lkq * 4 + 2][lrow] = av.z; As[lkq * 4 + 3][lrow] = av.w;
        Bs[lkq * 4 + 0][lrow] = wv.x; Bs[lkq * 4 + 1][lrow] = wv.y;
        Bs[lkq * 4 + 2][lrow] = wv.z; Bs[lkq * 4 + 3][lrow] = wv.w;
        __syncthreads();
        #pragma unroll
        for (int k = 0; k < GK; ++k) {
            float4 a4 = *reinterpret_cast<const float4*>(&As[k][tm * 4]);
            float4 b4 = *reinterpret_cast<const float4*>(&Bs[k][tn * 4]);
            acc[0][0] = fmaf(a4.x, b4.x, acc[0][0]); acc[0][1] = fmaf(a4.x, b4.y, acc[0][1]);
            acc[0][2] = fmaf(a4.x, b4.z, acc[0][2]); acc[0][3] = fmaf(a4.x, b4.w, acc[0][3]);
            acc[1][0] = fmaf(a4.y, b4.x, acc[1][0]); acc[1][1] = fmaf(a4.y, b4.y, acc[1][1]);
            acc[1][2] = fmaf(a4.y, b4.z, acc[1][2]); acc[1][3] = fmaf(a4.y, b4.w, acc[1][3]);
            acc[2][0] = fmaf(a4.z, b4.x, acc[2][0]); acc[2][1] = fmaf(a4.z, b4.y, acc[2][1]);
            acc[2][2] = fmaf(a4.z, b4.z, acc[2][2]); acc[2][3] = fmaf(a4.z, b4.w, acc[2][3]);
            acc[3][0] = fmaf(a4.w, b4.x, acc[3][0]); acc[3][1] = fmaf(a4.w, b4.y, acc[3][1]);
            acc[3][2] = fmaf(a4.w, b4.z, acc[3][2]); acc[3][3] = fmaf(a4.w, b4.w, acc[3][3]);
        }
    }

    float4 bb = *reinterpret_cast<const float4*>(&bias[n0 + tn * 4]);
    #pragma unroll
    for (int i = 0; i < 4; ++i) {
        int m = m0 + tm * 4 + i;
        float4 o;
        o.x = acc[i][0] + bb.x; o.y = acc[i][1] + bb.y;
        o.z = acc[i][2] + bb.z; o.w = acc[i][3] + bb.w;
        *reinterpret_cast<float4*>(&C[(size_t)m * N + n0 + tn * 4]) = o;
    }
}

// ---------------- host launcher ----------------
extern "C" void kernel_launch(void* const* d_in, const int* in_sizes, int n_in,
                              void* d_out, int out_size, void* d_ws, size_t ws_size,
                              hipStream_t stream) {
    (void)in_sizes; (void)n_in; (void)out_size; (void)ws_size;
    const float* x    = (const float*)d_in[0];
    const float* Wih0 = (const float*)d_in[1];
    const float* Whh0 = (const float*)d_in[2];
    const float* bih0 = (const float*)d_in[3];
    const float* bhh0 = (const float*)d_in[4];
    const float* Wih1 = (const float*)d_in[5];
    const float* Whh1 = (const float*)d_in[6];
    const float* bih1 = (const float*)d_in[7];
    const float* bhh1 = (const float*)d_in[8];
    const float* fcW  = (const float*)d_in[9];
    const float* fcb  = (const float*)d_in[10];

    float* out = (float*)d_out;                       // [B,T,O]
    float* hid = out + (size_t)Bsz * Tt * Osz;        // [L,B,H]

    char* ws = (char*)d_ws;
    const size_t xp_off    = 0;
    const size_t hall_off  = xp_off + (size_t)Bsz * Tt * G3 * 4;
    const size_t hbuf_off  = hall_off + (size_t)Bsz * Tt * Hsz * 4;
    const size_t flags_off = hbuf_off + (size_t)2 * Bsz * Hsz * 4;
    float* xp    = (float*)(ws + xp_off);
    float* hall  = (float*)(ws + hall_off);
    float* hbuf  = (float*)(ws + hbuf_off);
    int*   flags = (int*)  (ws + flags_off);

    hipLaunchKernelGGL(init_flags, dim3(16), dim3(256), 0, stream, flags);

    // layer 0 input projection: xp = x @ Wih0^T + bih0   (M=16384, N=1536, K=256)
    hipLaunchKernelGGL(gemm_nt_bias, dim3(G3 / GN, (Bsz * Tt) / GM), dim3(256), 0, stream,
                       x, Wih0, bih0, xp, Bsz * Tt, G3, Isz);

    // layer 0 recurrence
    hipLaunchKernelGGL(gru_rec, dim3(NBLK), dim3(TPB), 0, stream,
                       xp, Whh0, bhh0, hall, hbuf, flags, hid, 0);

    // layer 1 input projection: xp = hall @ Wih1^T + bih1  (M=16384, N=1536, K=512)
    hipLaunchKernelGGL(gemm_nt_bias, dim3(G3 / GN, (Bsz * Tt) / GM), dim3(256), 0, stream,
                       hall, Wih1, bih1, xp, Bsz * Tt, G3, Hsz);

    // layer 1 recurrence (overwrites hall)
    hipLaunchKernelGGL(gru_rec, dim3(NBLK), dim3(TPB), 0, stream,
                       xp, Whh1, bhh1, hall, hbuf, flags, hid + Bsz * Hsz, 513);

    // FC: out = hall @ fcW^T + fcb  (M=16384, N=128, K=512)
    hipLaunchKernelGGL(gemm_nt_bias, dim3(Osz / GN, (Bsz * Tt) / GM), dim3(256), 0, stream,
                       hall, fcW, fcb, out, Bsz * Tt, Osz, Hsz);
}

// Round 3
// 7879.618 us; speedup vs baseline: 7.0939x; 4.8070x over previous
//
#include <hip/hip_runtime.h>
#include <math.h>

// Problem constants
#define Bsz 32
#define Tt  512
#define Isz 256
#define Hsz 512
#define G3  1536
#define Osz 128

// Recurrence kernel config
#define NBLK 256
#define TPB  256
#define FLAG_STRIDE 16   // ints (64B) between flags

typedef float f4 __attribute__((ext_vector_type(4)));

// ---------------- coherent (IC-level) access helpers ----------------
// sc0 sc1 = bypass L1/L2, operate at the Infinity Cache (device coherence
// point). No cache-wide fences needed anywhere.
__device__ __forceinline__ void gstore_cv(float* p, float v) {
    asm volatile("global_store_dword %0, %1, off sc0 sc1" :: "v"(p), "v"(v) : "memory");
}
__device__ __forceinline__ void gstore_cv_i(int* p, int v) {
    asm volatile("global_store_dword %0, %1, off sc0 sc1" :: "v"(p), "v"(v) : "memory");
}

// ---------------- init flags ----------------
__global__ void init_flags(int* flags) {
    int i = threadIdx.x + blockIdx.x * blockDim.x;
    int n = NBLK * FLAG_STRIDE;
    for (; i < n; i += blockDim.x * gridDim.x) flags[i] = 0;
}

// ---------------- grid barrier ----------------
// Per-wave: drain own stores (write-through sc0sc1 -> at IC once vmcnt=0),
// sync block, tid0 publishes flag (sc0sc1), wave 0 polls all 256 flags with
// pipelined sc0sc1 loads. No fences, no atomics.
__device__ __forceinline__ void gbar(int* flags, int nb, int tid, int gen) {
    asm volatile("s_waitcnt vmcnt(0)" ::: "memory");
    __syncthreads();
    if (tid == 0) {
        gstore_cv_i(&flags[nb * FLAG_STRIDE], gen);
    }
    if (tid < 64) {
        int* f0 = &flags[(tid * 4 + 0) * FLAG_STRIDE];
        int* f1 = &flags[(tid * 4 + 1) * FLAG_STRIDE];
        int* f2 = &flags[(tid * 4 + 2) * FLAG_STRIDE];
        int* f3 = &flags[(tid * 4 + 3) * FLAG_STRIDE];
        for (;;) {
            int m0, m1, m2, m3;
            asm volatile(
                "global_load_dword %0, %4, off sc0 sc1\n\t"
                "global_load_dword %1, %5, off sc0 sc1\n\t"
                "global_load_dword %2, %6, off sc0 sc1\n\t"
                "global_load_dword %3, %7, off sc0 sc1\n\t"
                "s_waitcnt vmcnt(0)"
                : "=&v"(m0), "=&v"(m1), "=&v"(m2), "=&v"(m3)
                : "v"(f0), "v"(f1), "v"(f2), "v"(f3)
                : "memory");
            int ok = (m0 >= gen) && (m1 >= gen) && (m2 >= gen) && (m3 >= gen);
            if (__all(ok)) break;
            __builtin_amdgcn_s_sleep(2);
        }
    }
    __syncthreads();
}

__device__ __forceinline__ float sigf(float x) { return 1.0f / (1.0f + expf(-x)); }

// ---------------- persistent GRU recurrence (one layer) ----------------
__global__ void __launch_bounds__(TPB, 1) gru_rec(
    const float* __restrict__ xp,    // [B*T, 3H] (includes b_ih)
    const float* __restrict__ Whh,   // [3H, H]
    const float* __restrict__ bhh,   // [3H]
    float* __restrict__ hall,        // [B*T, H]
    float* __restrict__ hbuf,        // [2][B*H]
    int* __restrict__ flags,
    float* __restrict__ hid_out,     // [B*H] slice of d_out hidden
    int gen_base)
{
    const int tid = threadIdx.x;
    const int nb  = blockIdx.x;
    const int kc  = tid & 15;          // k-chunk selector
    const int jl  = (tid >> 4) & 1;    // which of the 2 owned columns
    const int bq  = tid >> 5;          // batch quad 0..7
    const int j0  = nb * 2;
    const int j   = j0 + jl;

    __shared__ float hsh[Bsz * Hsz];   // 64KB; also reused for W staging

    // ---- stage W_hh rows (6 rows x 512) into LDS, then registers ----
    for (int i = 0; i < 12; ++i) {
        int idx = i * TPB + tid;       // 0..3071
        int rl  = idx >> 9;            // row-local 0..5
        int col = idx & 511;
        int grow = (rl >> 1) * Hsz + j0 + (rl & 1);
        hsh[idx] = Whh[(size_t)grow * Hsz + col];
    }
    __syncthreads();
    float4 wreg[3][8];
    #pragma unroll
    for (int g = 0; g < 3; ++g) {
        int rl = g * 2 + jl;
        #pragma unroll
        for (int q = 0; q < 8; ++q)
            wreg[g][q] = *reinterpret_cast<const float4*>(&hsh[rl * Hsz + q * 64 + kc * 4]);
    }
    __syncthreads();

    const float bh0 = bhh[0 * Hsz + j];
    const float bh1 = bhh[1 * Hsz + j];
    const float bh2 = bhh[2 * Hsz + j];

    // ---- zero h0 into hbuf[0] (IC-coherent stores) ----
    if (kc == 0) {
        #pragma unroll
        for (int bi = 0; bi < 4; ++bi) {
            int b = bq * 4 + bi;
            gstore_cv(&hbuf[b * Hsz + j], 0.0f);
        }
    }
    gbar(flags, nb, tid, gen_base + 1);

    for (int t = 0; t < Tt; ++t) {
        const float* hsrc = hbuf + (size_t)(t & 1) * (Bsz * Hsz);
        float*       hdst = hbuf + (size_t)((t + 1) & 1) * (Bsz * Hsz);

        // xp for the owner lanes (plain cached loads; producer kernel ended)
        float xr[4], xz[4], xn[4];
        if (kc == 0) {
            #pragma unroll
            for (int bi = 0; bi < 4; ++bi) {
                int b = bq * 4 + bi;
                const float* p = xp + (size_t)(b * Tt + t) * G3;
                xr[bi] = p[j];
                xz[bi] = p[Hsz + j];
                xn[bi] = p[2 * Hsz + j];
            }
        }

        // ---- stage h(t) into LDS: 16 pipelined sc0sc1 dwordx4 loads ----
        {
            const f4* s4 = reinterpret_cast<const f4*>(hsrc);
            f4* hsh4 = reinterpret_cast<f4*>(hsh);
            f4 r0, r1, r2, r3, r4, r5, r6, r7, r8, r9, r10, r11, r12, r13, r14, r15;
            #define GLD(r, i) asm volatile("global_load_dwordx4 %0, %1, off sc0 sc1" \
                                           : "=&v"(r) : "v"(s4 + (i) * TPB + tid))
            GLD(r0, 0);  GLD(r1, 1);  GLD(r2, 2);  GLD(r3, 3);
            GLD(r4, 4);  GLD(r5, 5);  GLD(r6, 6);  GLD(r7, 7);
            GLD(r8, 8);  GLD(r9, 9);  GLD(r10, 10); GLD(r11, 11);
            GLD(r12, 12); GLD(r13, 13); GLD(r14, 14); GLD(r15, 15);
            #undef GLD
            asm volatile("s_waitcnt vmcnt(0)" ::: "memory");
            hsh4[0 * TPB + tid] = r0;   hsh4[1 * TPB + tid] = r1;
            hsh4[2 * TPB + tid] = r2;   hsh4[3 * TPB + tid] = r3;
            hsh4[4 * TPB + tid] = r4;   hsh4[5 * TPB + tid] = r5;
            hsh4[6 * TPB + tid] = r6;   hsh4[7 * TPB + tid] = r7;
            hsh4[8 * TPB + tid] = r8;   hsh4[9 * TPB + tid] = r9;
            hsh4[10 * TPB + tid] = r10; hsh4[11 * TPB + tid] = r11;
            hsh4[12 * TPB + tid] = r12; hsh4[13 * TPB + tid] = r13;
            hsh4[14 * TPB + tid] = r14; hsh4[15 * TPB + tid] = r15;
        }
        __syncthreads();

        // partial dot products: gates r,z,n for column j, 4 batches
        float acc[3][4];
        #pragma unroll
        for (int g = 0; g < 3; ++g)
            #pragma unroll
            for (int bi = 0; bi < 4; ++bi) acc[g][bi] = 0.0f;

        #pragma unroll
        for (int bi = 0; bi < 4; ++bi) {
            int b = bq * 4 + bi;
            const float4* hp = reinterpret_cast<const float4*>(&hsh[b * Hsz]);
            float4 h4[8];
            #pragma unroll
            for (int q = 0; q < 8; ++q) h4[q] = hp[q * 16 + kc];
            #pragma unroll
            for (int g = 0; g < 3; ++g) {
                float s = 0.0f;
                #pragma unroll
                for (int q = 0; q < 8; ++q) {
                    s = fmaf(wreg[g][q].x, h4[q].x, s);
                    s = fmaf(wreg[g][q].y, h4[q].y, s);
                    s = fmaf(wreg[g][q].z, h4[q].z, s);
                    s = fmaf(wreg[g][q].w, h4[q].w, s);
                }
                acc[g][bi] = s;
            }
        }

        // reduce across the 16 kc lanes (low 4 lane bits)
        #pragma unroll
        for (int off = 1; off < 16; off <<= 1) {
            #pragma unroll
            for (int g = 0; g < 3; ++g)
                #pragma unroll
                for (int bi = 0; bi < 4; ++bi)
                    acc[g][bi] += __shfl_xor(acc[g][bi], off, 64);
        }

        if (kc == 0) {
            #pragma unroll
            for (int bi = 0; bi < 4; ++bi) {
                int b = bq * 4 + bi;
                float ghr = acc[0][bi] + bh0;
                float ghz = acc[1][bi] + bh1;
                float ghn = acc[2][bi] + bh2;
                float r = sigf(xr[bi] + ghr);
                float z = sigf(xz[bi] + ghz);
                float n = tanhf(xn[bi] + r * ghn);
                float ho = hsh[b * Hsz + j];
                float hv = (1.0f - z) * n + z * ho;
                gstore_cv(&hdst[b * Hsz + j], hv);      // IC-coherent publish
                hall[(size_t)(b * Tt + t) * Hsz + j] = hv;  // plain (kernel-end flush)
                if (t == Tt - 1) hid_out[b * Hsz + j] = hv;
            }
        }

        gbar(flags, nb, tid, gen_base + t + 2);
    }
}

// ---------------- fp32 GEMM: C[M,N] = A[M,K] * W[N,K]^T + bias[N] ----------------
#define GM 64
#define GN 64
#define GK 16
__global__ void __launch_bounds__(256) gemm_nt_bias(
    const float* __restrict__ A, const float* __restrict__ W,
    const float* __restrict__ bias, float* __restrict__ C,
    int M, int N, int K)
{
    __shared__ float As[GK][GM];
    __shared__ float Bs[GK][GN];
    const int tid = threadIdx.x;
    const int n0 = blockIdx.x * GN;
    const int m0 = blockIdx.y * GM;
    const int tn = tid & 15;
    const int tm = tid >> 4;
    const int lrow = tid >> 2;   // 0..63
    const int lkq  = tid & 3;    // 0..3

    float acc[4][4];
    #pragma unroll
    for (int i = 0; i < 4; ++i)
        #pragma unroll
        for (int jj = 0; jj < 4; ++jj) acc[i][jj] = 0.0f;

    for (int k0 = 0; k0 < K; k0 += GK) {
        float4 av = *reinterpret_cast<const float4*>(&A[(size_t)(m0 + lrow) * K + k0 + lkq * 4]);
        float4 wv = *reinterpret_cast<const float4*>(&W[(size_t)(n0 + lrow) * K + k0 + lkq * 4]);
        __syncthreads();
        As[lkq * 4 + 0][lrow] = av.x; As[lkq * 4 + 1][lrow] = av.y;
        As[lkq * 4 + 2][lrow] = av.z; As[lkq * 4 + 3][lrow] = av.w;
        Bs[lkq * 4 + 0][lrow] = wv.x; Bs[lkq * 4 + 1][lrow] = wv.y;
        Bs[lkq * 4 + 2][lrow] = wv.z; Bs[lkq * 4 + 3][lrow] = wv.w;
        __syncthreads();
        #pragma unroll
        for (int k = 0; k < GK; ++k) {
            float4 a4 = *reinterpret_cast<const float4*>(&As[k][tm * 4]);
            float4 b4 = *reinterpret_cast<const float4*>(&Bs[k][tn * 4]);
            acc[0][0] = fmaf(a4.x, b4.x, acc[0][0]); acc[0][1] = fmaf(a4.x, b4.y, acc[0][1]);
            acc[0][2] = fmaf(a4.x, b4.z, acc[0][2]); acc[0][3] = fmaf(a4.x, b4.w, acc[0][3]);
            acc[1][0] = fmaf(a4.y, b4.x, acc[1][0]); acc[1][1] = fmaf(a4.y, b4.y, acc[1][1]);
            acc[1][2] = fmaf(a4.y, b4.z, acc[1][2]); acc[1][3] = fmaf(a4.y, b4.w, acc[1][3]);
            acc[2][0] = fmaf(a4.z, b4.x, acc[2][0]); acc[2][1] = fmaf(a4.z, b4.y, acc[2][1]);
            acc[2][2] = fmaf(a4.z, b4.z, acc[2][2]); acc[2][3] = fmaf(a4.z, b4.w, acc[2][3]);
            acc[3][0] = fmaf(a4.w, b4.x, acc[3][0]); acc[3][1] = fmaf(a4.w, b4.y, acc[3][1]);
            acc[3][2] = fmaf(a4.w, b4.z, acc[3][2]); acc[3][3] = fmaf(a4.w, b4.w, acc[3][3]);
        }
    }

    float4 bb = *reinterpret_cast<const float4*>(&bias[n0 + tn * 4]);
    #pragma unroll
    for (int i = 0; i < 4; ++i) {
        int m = m0 + tm * 4 + i;
        float4 o;
        o.x = acc[i][0] + bb.x; o.y = acc[i][1] + bb.y;
        o.z = acc[i][2] + bb.z; o.w = acc[i][3] + bb.w;
        *reinterpret_cast<float4*>(&C[(size_t)m * N + n0 + tn * 4]) = o;
    }
}

// ---------------- host launcher ----------------
extern "C" void kernel_launch(void* const* d_in, const int* in_sizes, int n_in,
                              void* d_out, int out_size, void* d_ws, size_t ws_size,
                              hipStream_t stream) {
    (void)in_sizes; (void)n_in; (void)out_size; (void)ws_size;
    const float* x    = (const float*)d_in[0];
    const float* Wih0 = (const float*)d_in[1];
    const float* Whh0 = (const float*)d_in[2];
    const float* bih0 = (const float*)d_in[3];
    const float* bhh0 = (const float*)d_in[4];
    const float* Wih1 = (const float*)d_in[5];
    const float* Whh1 = (const float*)d_in[6];
    const float* bih1 = (const float*)d_in[7];
    const float* bhh1 = (const float*)d_in[8];
    const float* fcW  = (const float*)d_in[9];
    const float* fcb  = (const float*)d_in[10];

    float* out = (float*)d_out;                       // [B,T,O]
    float* hid = out + (size_t)Bsz * Tt * Osz;        // [L,B,H]

    char* ws = (char*)d_ws;
    const size_t xp_off    = 0;
    const size_t hall_off  = xp_off + (size_t)Bsz * Tt * G3 * 4;
    const size_t hbuf_off  = hall_off + (size_t)Bsz * Tt * Hsz * 4;
    const size_t flags_off = hbuf_off + (size_t)2 * Bsz * Hsz * 4;
    float* xp    = (float*)(ws + xp_off);
    float* hall  = (float*)(ws + hall_off);
    float* hbuf  = (float*)(ws + hbuf_off);
    int*   flags = (int*)  (ws + flags_off);

    hipLaunchKernelGGL(init_flags, dim3(16), dim3(256), 0, stream, flags);

    // layer 0 input projection: xp = x @ Wih0^T + bih0   (M=16384, N=1536, K=256)
    hipLaunchKernelGGL(gemm_nt_bias, dim3(G3 / GN, (Bsz * Tt) / GM), dim3(256), 0, stream,
                       x, Wih0, bih0, xp, Bsz * Tt, G3, Isz);

    // layer 0 recurrence
    hipLaunchKernelGGL(gru_rec, dim3(NBLK), dim3(TPB), 0, stream,
                       xp, Whh0, bhh0, hall, hbuf, flags, hid, 0);

    // layer 1 input projection: xp = hall @ Wih1^T + bih1  (M=16384, N=1536, K=512)
    hipLaunchKernelGGL(gemm_nt_bias, dim3(G3 / GN, (Bsz * Tt) / GM), dim3(256), 0, stream,
                       hall, Wih1, bih1, xp, Bsz * Tt, G3, Hsz);

    // layer 1 recurrence (overwrites hall)
    hipLaunchKernelGGL(gru_rec, dim3(NBLK), dim3(TPB), 0, stream,
                       xp, Whh1, bhh1, hall, hbuf, flags, hid + Bsz * Hsz, 513);

    // FC: out = hall @ fcW^T + fcb  (M=16384, N=128, K=512)
    hipLaunchKernelGGL(gemm_nt_bias, dim3(Osz / GN, (Bsz * Tt) / GM), dim3(256), 0, stream,
                       hall, fcW, fcb, out, Bsz * Tt, Osz, Hsz);
}

// Round 4
// 6541.883 us; speedup vs baseline: 8.5445x; 1.2045x over previous
//
#include <hip/hip_runtime.h>
#include <math.h>

// Problem constants
#define Bsz 32
#define Tt  512
#define Isz 256
#define Hsz 512
#define G3  1536
#define Osz 128

// Recurrence config: 128 blocks x 512 threads, each block owns 4 h-columns.
#define NBLK 128
#define TPB  512
#define G0_L0 1u
#define G0_L1 4096u

typedef float f4  __attribute__((ext_vector_type(4)));
typedef unsigned int u32;
typedef u32 u32x2 __attribute__((ext_vector_type(2)));
typedef u32 u32x4 __attribute__((ext_vector_type(4)));

__device__ __forceinline__ float sigf(float x) { return 1.0f / (1.0f + expf(-x)); }

// ---------------- init pbuf: slot0 = (h0=0, gen0), slot1 = invalid ----------------
// Plain stores: kernel-end L2 writeback makes them visible to later sc0sc1 reads.
__global__ void init_pbuf(u32x2* pbuf, u32 gen0) {
    int i = threadIdx.x + blockIdx.x * blockDim.x;
    const int n = Bsz * Hsz;
    for (; i < n; i += gridDim.x * blockDim.x) {
        pbuf[i]     = (u32x2){0u, gen0};   // slot 0: h0 = 0, valid with gen0
        pbuf[n + i] = (u32x2){0u, 0u};     // slot 1: gen invalid
    }
}

// ---------------- persistent GRU recurrence (one layer), flagless ----------------
// h(t) lives in pbuf slot t&1 as (val,gen) pairs with gen = g0 + t.
// Step t: poll slot t&1 for gen g0+t -> LDS -> compute h(t+1) -> publish to
// slot (t+1)&1 with gen g0+t+1. No grid barrier; dataflow self-synchronizes.
__global__ void __launch_bounds__(TPB, 1) gru_rec(
    const float* __restrict__ xp,    // [B*T, 3H] (includes b_ih)
    const float* __restrict__ Whh,   // [3H, H]
    const float* __restrict__ bhh,   // [3H]
    float* __restrict__ hall,        // [B*T, H]
    u32x2* __restrict__ pbuf,        // [2][B*H] (val,gen) pairs
    float* __restrict__ hid_out,     // [B*H] slice of d_out hidden
    u32 g0)
{
    const int tid = threadIdx.x;
    const int s   = blockIdx.x;        // column chunk
    const int kc  = tid & 15;          // k-slice selector (16 slices of 32)
    const int jl  = (tid >> 4) & 3;    // which of the 4 owned columns
    const int bq  = tid >> 6;          // batch quad 0..7
    const int j   = s * 4 + jl;

    __shared__ float hsh[Bsz * Hsz];   // 64KB; reused for W staging

    // ---- stage W_hh rows (12 rows x 512) into LDS, then registers ----
    for (int i = 0; i < 12; ++i) {
        int idx = i * TPB + tid;       // 0..6143
        int rl  = idx >> 9;            // row-local 0..11  (g = rl>>2, jl = rl&3)
        int col = idx & 511;
        int grow = (rl >> 2) * Hsz + s * 4 + (rl & 3);
        hsh[idx] = Whh[(size_t)grow * Hsz + col];
    }
    __syncthreads();
    f4 wreg[3][8];
    #pragma unroll
    for (int g = 0; g < 3; ++g) {
        #pragma unroll
        for (int q = 0; q < 8; ++q)
            wreg[g][q] = *reinterpret_cast<const f4*>(&hsh[(g * 4 + jl) * Hsz + q * 64 + kc * 4]);
    }
    __syncthreads();

    const float bh0 = bhh[0 * Hsz + j];
    const float bh1 = bhh[1 * Hsz + j];
    const float bh2 = bhh[2 * Hsz + j];

    for (int t = 0; t < Tt; ++t) {
        const u32 rg = g0 + (u32)t;        // expected gen of h(t)
        const u32 wg = rg + 1u;            // gen for h(t+1)
        const u32x4* src = reinterpret_cast<const u32x4*>(
            pbuf + (size_t)(t & 1) * (Bsz * Hsz));            // 8192 x4 units
        u32x2* dst = pbuf + (size_t)((t + 1) & 1) * (Bsz * Hsz);

        // xp for the owner lanes (plain cached loads, issued before poll)
        float xr[4], xz[4], xn[4];
        if (kc == 0) {
            #pragma unroll
            for (int bi = 0; bi < 4; ++bi) {
                int b = bq * 4 + bi;
                const float* p = xp + (size_t)(b * Tt + t) * G3;
                xr[bi] = p[j];
                xz[bi] = p[Hsz + j];
                xn[bi] = p[2 * Hsz + j];
            }
        }

        // ---- poll + stage: 16 self-validating (val,gen,val,gen) x4 loads ----
        u32x4 r[16];
        for (;;) {
            #pragma unroll
            for (int i = 0; i < 16; ++i) {
                asm volatile("global_load_dwordx4 %0, %1, off sc0 sc1"
                             : "=&v"(r[i]) : "v"(src + i * TPB + tid));
            }
            asm volatile("s_waitcnt vmcnt(0)" ::: "memory");
            bool ok = true;
            #pragma unroll
            for (int i = 0; i < 16; ++i)
                ok = ok && (r[i][1] == rg) && (r[i][3] == rg);
            if (ok) break;
            __builtin_amdgcn_s_sleep(1);
        }

        // strip gens -> LDS (float2 per x4-unit, conflict-free b64 writes)
        {
            float2* hsh2 = reinterpret_cast<float2*>(hsh);
            #pragma unroll
            for (int i = 0; i < 16; ++i) {
                int u = i * TPB + tid;     // pair-unit index: h elems 2u, 2u+1
                float2 v;
                v.x = __uint_as_float(r[i][0]);
                v.y = __uint_as_float(r[i][2]);
                hsh2[u] = v;
            }
        }
        __syncthreads();

        // partial dot products: gates r,z,n for column j, 4 batches
        float acc[3][4];
        #pragma unroll
        for (int g = 0; g < 3; ++g)
            #pragma unroll
            for (int bi = 0; bi < 4; ++bi) acc[g][bi] = 0.0f;

        #pragma unroll
        for (int bi = 0; bi < 4; ++bi) {
            int b = bq * 4 + bi;
            const f4* hp = reinterpret_cast<const f4*>(&hsh[b * Hsz]);
            f4 h4[8];
            #pragma unroll
            for (int q = 0; q < 8; ++q) h4[q] = hp[q * 16 + kc];   // consecutive across kc
            #pragma unroll
            for (int g = 0; g < 3; ++g) {
                float ssum = 0.0f;
                #pragma unroll
                for (int q = 0; q < 8; ++q) {
                    ssum = fmaf(wreg[g][q][0], h4[q][0], ssum);
                    ssum = fmaf(wreg[g][q][1], h4[q][1], ssum);
                    ssum = fmaf(wreg[g][q][2], h4[q][2], ssum);
                    ssum = fmaf(wreg[g][q][3], h4[q][3], ssum);
                }
                acc[g][bi] = ssum;
            }
        }

        // reduce across the 16 kc lanes (low 4 lane bits)
        #pragma unroll
        for (int off = 1; off < 16; off <<= 1) {
            #pragma unroll
            for (int g = 0; g < 3; ++g)
                #pragma unroll
                for (int bi = 0; bi < 4; ++bi)
                    acc[g][bi] += __shfl_xor(acc[g][bi], off, 64);
        }

        if (kc == 0) {
            #pragma unroll
            for (int bi = 0; bi < 4; ++bi) {
                int b = bq * 4 + bi;
                float ghr = acc[0][bi] + bh0;
                float ghz = acc[1][bi] + bh1;
                float ghn = acc[2][bi] + bh2;
                float rr = sigf(xr[bi] + ghr);
                float zz = sigf(xz[bi] + ghz);
                float nn = tanhf(xn[bi] + rr * ghn);
                float ho = hsh[b * Hsz + j];
                float hv = (1.0f - zz) * nn + zz * ho;
                u32x2 pk = (u32x2){__float_as_uint(hv), wg};
                asm volatile("global_store_dwordx2 %0, %1, off sc0 sc1"
                             :: "v"(dst + b * Hsz + j), "v"(pk) : "memory");
                hall[(size_t)(b * Tt + t) * Hsz + j] = hv;   // plain (kernel-end flush)
                if (t == Tt - 1) hid_out[b * Hsz + j] = hv;
            }
        }

        __syncthreads();   // protect hsh before next step's LDS overwrite
    }
}

// ---------------- fp32 GEMM: C[M,N] = A[M,K] * W[N,K]^T + bias[N] ----------------
#define GM 64
#define GN 64
#define GK 16
__global__ void __launch_bounds__(256) gemm_nt_bias(
    const float* __restrict__ A, const float* __restrict__ W,
    const float* __restrict__ bias, float* __restrict__ C,
    int M, int N, int K)
{
    __shared__ float As[GK][GM];
    __shared__ float Bs[GK][GN];
    const int tid = threadIdx.x;
    const int n0 = blockIdx.x * GN;
    const int m0 = blockIdx.y * GM;
    const int tn = tid & 15;
    const int tm = tid >> 4;
    const int lrow = tid >> 2;   // 0..63
    const int lkq  = tid & 3;    // 0..3

    float acc[4][4];
    #pragma unroll
    for (int i = 0; i < 4; ++i)
        #pragma unroll
        for (int jj = 0; jj < 4; ++jj) acc[i][jj] = 0.0f;

    for (int k0 = 0; k0 < K; k0 += GK) {
        float4 av = *reinterpret_cast<const float4*>(&A[(size_t)(m0 + lrow) * K + k0 + lkq * 4]);
        float4 wv = *reinterpret_cast<const float4*>(&W[(size_t)(n0 + lrow) * K + k0 + lkq * 4]);
        __syncthreads();
        As[lkq * 4 + 0][lrow] = av.x; As[lkq * 4 + 1][lrow] = av.y;
        As[lkq * 4 + 2][lrow] = av.z; As[lkq * 4 + 3][lrow] = av.w;
        Bs[lkq * 4 + 0][lrow] = wv.x; Bs[lkq * 4 + 1][lrow] = wv.y;
        Bs[lkq * 4 + 2][lrow] = wv.z; Bs[lkq * 4 + 3][lrow] = wv.w;
        __syncthreads();
        #pragma unroll
        for (int k = 0; k < GK; ++k) {
            float4 a4 = *reinterpret_cast<const float4*>(&As[k][tm * 4]);
            float4 b4 = *reinterpret_cast<const float4*>(&Bs[k][tn * 4]);
            acc[0][0] = fmaf(a4.x, b4.x, acc[0][0]); acc[0][1] = fmaf(a4.x, b4.y, acc[0][1]);
            acc[0][2] = fmaf(a4.x, b4.z, acc[0][2]); acc[0][3] = fmaf(a4.x, b4.w, acc[0][3]);
            acc[1][0] = fmaf(a4.y, b4.x, acc[1][0]); acc[1][1] = fmaf(a4.y, b4.y, acc[1][1]);
            acc[1][2] = fmaf(a4.y, b4.z, acc[1][2]); acc[1][3] = fmaf(a4.y, b4.w, acc[1][3]);
            acc[2][0] = fmaf(a4.z, b4.x, acc[2][0]); acc[2][1] = fmaf(a4.z, b4.y, acc[2][1]);
            acc[2][2] = fmaf(a4.z, b4.z, acc[2][2]); acc[2][3] = fmaf(a4.z, b4.w, acc[2][3]);
            acc[3][0] = fmaf(a4.w, b4.x, acc[3][0]); acc[3][1] = fmaf(a4.w, b4.y, acc[3][1]);
            acc[3][2] = fmaf(a4.w, b4.z, acc[3][2]); acc[3][3] = fmaf(a4.w, b4.w, acc[3][3]);
        }
    }

    float4 bb = *reinterpret_cast<const float4*>(&bias[n0 + tn * 4]);
    #pragma unroll
    for (int i = 0; i < 4; ++i) {
        int m = m0 + tm * 4 + i;
        float4 o;
        o.x = acc[i][0] + bb.x; o.y = acc[i][1] + bb.y;
        o.z = acc[i][2] + bb.z; o.w = acc[i][3] + bb.w;
        *reinterpret_cast<float4*>(&C[(size_t)m * N + n0 + tn * 4]) = o;
    }
}

// ---------------- host launcher ----------------
extern "C" void kernel_launch(void* const* d_in, const int* in_sizes, int n_in,
                              void* d_out, int out_size, void* d_ws, size_t ws_size,
                              hipStream_t stream) {
    (void)in_sizes; (void)n_in; (void)out_size; (void)ws_size;
    const float* x    = (const float*)d_in[0];
    const float* Wih0 = (const float*)d_in[1];
    const float* Whh0 = (const float*)d_in[2];
    const float* bih0 = (const float*)d_in[3];
    const float* bhh0 = (const float*)d_in[4];
    const float* Wih1 = (const float*)d_in[5];
    const float* Whh1 = (const float*)d_in[6];
    const float* bih1 = (const float*)d_in[7];
    const float* bhh1 = (const float*)d_in[8];
    const float* fcW  = (const float*)d_in[9];
    const float* fcb  = (const float*)d_in[10];

    float* out = (float*)d_out;                       // [B,T,O]
    float* hid = out + (size_t)Bsz * Tt * Osz;        // [L,B,H]

    char* ws = (char*)d_ws;
    const size_t xp_off   = 0;
    const size_t hall_off = xp_off + (size_t)Bsz * Tt * G3 * 4;
    const size_t pbuf_off = hall_off + (size_t)Bsz * Tt * Hsz * 4;   // 2*B*H*8B = 256KB
    float* xp    = (float*)(ws + xp_off);
    float* hall  = (float*)(ws + hall_off);
    u32x2* pbuf  = (u32x2*)(ws + pbuf_off);

    // layer 0 input projection: xp = x @ Wih0^T + bih0   (M=16384, N=1536, K=256)
    hipLaunchKernelGGL(gemm_nt_bias, dim3(G3 / GN, (Bsz * Tt) / GM), dim3(256), 0, stream,
                       x, Wih0, bih0, xp, Bsz * Tt, G3, Isz);

    // init exchange buffer for layer 0, then recurrence
    hipLaunchKernelGGL(init_pbuf, dim3(64), dim3(256), 0, stream, pbuf, G0_L0);
    hipLaunchKernelGGL(gru_rec, dim3(NBLK), dim3(TPB), 0, stream,
                       xp, Whh0, bhh0, hall, pbuf, hid, G0_L0);

    // layer 1 input projection: xp = hall @ Wih1^T + bih1  (M=16384, N=1536, K=512)
    hipLaunchKernelGGL(gemm_nt_bias, dim3(G3 / GN, (Bsz * Tt) / GM), dim3(256), 0, stream,
                       hall, Wih1, bih1, xp, Bsz * Tt, G3, Hsz);

    // init exchange buffer for layer 1, then recurrence (overwrites hall)
    hipLaunchKernelGGL(init_pbuf, dim3(64), dim3(256), 0, stream, pbuf, G0_L1);
    hipLaunchKernelGGL(gru_rec, dim3(NBLK), dim3(TPB), 0, stream,
                       xp, Whh1, bhh1, hall, pbuf, hid + Bsz * Hsz, G0_L1);

    // FC: out = hall @ fcW^T + fcb  (M=16384, N=128, K=512)
    hipLaunchKernelGGL(gemm_nt_bias, dim3(Osz / GN, (Bsz * Tt) / GM), dim3(256), 0, stream,
                       hall, fcW, fcb, out, Bsz * Tt, Osz, Hsz);
}

// Round 5
// 4074.020 us; speedup vs baseline: 13.7204x; 1.6058x over previous
//
#include <hip/hip_runtime.h>
#include <math.h>

// Problem constants
#define Bsz 32
#define Tt  512
#define Isz 256
#define Hsz 512
#define G3  1536
#define Osz 128

// Recurrence config: 256 blocks = 32 batches x 8 col-groups; 1024 threads.
#define NBLK 256
#define TPB  1024
#define G0_L0 1u
#define G0_L1 4096u

typedef float f4  __attribute__((ext_vector_type(4)));
typedef unsigned int u32;
typedef u32 u32x2 __attribute__((ext_vector_type(2)));

__device__ __forceinline__ float sigf(float x) { return 1.0f / (1.0f + expf(-x)); }

// ---------------- init pbuf: slot0 = (h0=0, gen0), slot1 = invalid ----------------
// Plain stores: kernel-end L2 writeback makes them visible to later sc0sc1 reads.
__global__ void init_pbuf(u32x2* pbuf, u32 gen0) {
    int i = threadIdx.x + blockIdx.x * blockDim.x;
    const int n = Bsz * Hsz;
    for (; i < n; i += gridDim.x * blockDim.x) {
        pbuf[i]     = (u32x2){0u, gen0};   // slot 0: h0 = 0, valid with gen0
        pbuf[n + i] = (u32x2){0u, 0u};     // slot 1: gen invalid
    }
}

// ---------------- persistent GRU recurrence (one layer), batch-split ----------------
// Block (b,p): batch b, output h-cols [p*64, p*64+64). Exchange is PER BATCH:
// pbuf[slot][b*H + i] (val,gen). Step t: waves 0-7 poll the 512 pairs of batch
// b for gen g0+t (one pair per lane), stage vals to LDS; all 16 waves compute;
// owner lanes publish 64 new pairs with gen g0+t+1. No grid barrier.
__global__ void __launch_bounds__(TPB) gru_rec(
    const float* __restrict__ xp,    // [B*T, 3H] (includes b_ih)
    const float* __restrict__ Whh,   // [3H, H]
    const float* __restrict__ bhh,   // [3H]
    float* __restrict__ hall,        // [B*T, H]
    u32x2* __restrict__ pbuf,        // [2][B*H] (val,gen)
    float* __restrict__ hid_out,     // [B*H] slice of d_out hidden
    u32 g0)
{
    const int tid  = threadIdx.x;
    const int b    = blockIdx.x >> 3;       // batch element
    const int p    = blockIdx.x & 7;        // col-group
    const int lane = tid & 63;
    const int w    = tid >> 6;              // wave 0..15
    const int kc   = lane & 15;             // k-chunk (16 chunks of 32)
    const int jl   = w * 4 + (lane >> 4);   // local col 0..63
    const int j    = p * 64 + jl;           // h-col within batch

    // LDS: h of batch b, 16 chunks of 32 floats, padded to 36 (bank spread)
    __shared__ float hsh[16 * 36];

    // ---- load my weights into registers: rows {g*512+j}, k in [kc*32,+32) ----
    f4 wreg[3][8];
    #pragma unroll
    for (int g = 0; g < 3; ++g) {
        const float* wp = Whh + (size_t)(g * Hsz + j) * Hsz + kc * 32;
        #pragma unroll
        for (int q = 0; q < 8; ++q)
            wreg[g][q] = *reinterpret_cast<const f4*>(wp + q * 4);
    }
    const float bh0 = bhh[0 * Hsz + j];
    const float bh1 = bhh[1 * Hsz + j];
    const float bh2 = bhh[2 * Hsz + j];

    for (int t = 0; t < Tt; ++t) {
        const u32 rg = g0 + (u32)t;
        const u32 wg = rg + 1u;
        const u32x2* src = pbuf + (size_t)(t & 1) * (Bsz * Hsz) + b * Hsz;
        u32x2*       dst = pbuf + (size_t)((t + 1) & 1) * (Bsz * Hsz) + b * Hsz;

        // xp for owner lanes (plain cached loads; issued before poll/compute)
        float xr = 0.f, xz = 0.f, xn = 0.f;
        if (kc == 0) {
            const float* pp = xp + (size_t)(b * Tt + t) * G3;
            xr = pp[j];
            xz = pp[Hsz + j];
            xn = pp[2 * Hsz + j];
        }

        // ---- waves 0-7: poll own 64 pairs, stage vals into LDS ----
        if (w < 8) {
            const int i = w * 64 + lane;           // h index 0..511
            const u32x2* sp = src + i;
            u32 val;
            for (;;) {
                u32x2 pr;
                asm volatile("global_load_dwordx2 %0, %1, off sc0 sc1\n\t"
                             "s_waitcnt vmcnt(0)"
                             : "=&v"(pr) : "v"(sp) : "memory");
                if (__all(pr[1] == rg)) { val = pr[0]; break; }
                __builtin_amdgcn_s_sleep(1);
            }
            hsh[(i >> 5) * 36 + (i & 31)] = __uint_as_float(val);
        }
        __syncthreads();

        // ---- compute: 3 gate partials over k in [kc*32, +32) ----
        f4 hh[8];
        {
            const f4* hp = reinterpret_cast<const f4*>(hsh) + kc * 9;  // 36/4=9
            #pragma unroll
            for (int q = 0; q < 8; ++q) hh[q] = hp[q];
        }
        float acc[3];
        #pragma unroll
        for (int g = 0; g < 3; ++g) {
            float s = 0.0f;
            #pragma unroll
            for (int q = 0; q < 8; ++q) {
                s = fmaf(wreg[g][q][0], hh[q][0], s);
                s = fmaf(wreg[g][q][1], hh[q][1], s);
                s = fmaf(wreg[g][q][2], hh[q][2], s);
                s = fmaf(wreg[g][q][3], hh[q][3], s);
            }
            acc[g] = s;
        }

        // reduce across 16 kc lanes (low 4 lane bits)
        #pragma unroll
        for (int off = 1; off < 16; off <<= 1) {
            #pragma unroll
            for (int g = 0; g < 3; ++g)
                acc[g] += __shfl_xor(acc[g], off, 64);
        }

        if (kc == 0) {
            float rr = sigf(xr + acc[0] + bh0);
            float zz = sigf(xz + acc[1] + bh1);
            float nn = tanhf(xn + rr * (acc[2] + bh2));
            float ho = hsh[(j >> 5) * 36 + (j & 31)];
            float hv = (1.0f - zz) * nn + zz * ho;
            u32x2 pk = (u32x2){__float_as_uint(hv), wg};
            asm volatile("global_store_dwordx2 %0, %1, off sc0 sc1"
                         :: "v"(dst + j), "v"(pk) : "memory");
            hall[(size_t)(b * Tt + t) * Hsz + j] = hv;       // plain
            if (t == Tt - 1) hid_out[b * Hsz + j] = hv;
        }

        __syncthreads();   // protect hsh before next step's staging
    }
}

// ---------------- fp32 GEMM: C[M,N] = A[M,K] * W[N,K]^T + bias[N] ----------------
#define GM 64
#define GN 64
#define GK 16
__global__ void __launch_bounds__(256) gemm_nt_bias(
    const float* __restrict__ A, const float* __restrict__ W,
    const float* __restrict__ bias, float* __restrict__ C,
    int M, int N, int K)
{
    __shared__ float As[GK][GM];
    __shared__ float Bs[GK][GN];
    const int tid = threadIdx.x;
    const int n0 = blockIdx.x * GN;
    const int m0 = blockIdx.y * GM;
    const int tn = tid & 15;
    const int tm = tid >> 4;
    const int lrow = tid >> 2;   // 0..63
    const int lkq  = tid & 3;    // 0..3

    float acc[4][4];
    #pragma unroll
    for (int i = 0; i < 4; ++i)
        #pragma unroll
        for (int jj = 0; jj < 4; ++jj) acc[i][jj] = 0.0f;

    for (int k0 = 0; k0 < K; k0 += GK) {
        float4 av = *reinterpret_cast<const float4*>(&A[(size_t)(m0 + lrow) * K + k0 + lkq * 4]);
        float4 wv = *reinterpret_cast<const float4*>(&W[(size_t)(n0 + lrow) * K + k0 + lkq * 4]);
        __syncthreads();
        As[lkq * 4 + 0][lrow] = av.x; As[lkq * 4 + 1][lrow] = av.y;
        As[lkq * 4 + 2][lrow] = av.z; As[lkq * 4 + 3][lrow] = av.w;
        Bs[lkq * 4 + 0][lrow] = wv.x; Bs[lkq * 4 + 1][lrow] = wv.y;
        Bs[lkq * 4 + 2][lrow] = wv.z; Bs[lkq * 4 + 3][lrow] = wv.w;
        __syncthreads();
        #pragma unroll
        for (int k = 0; k < GK; ++k) {
            float4 a4 = *reinterpret_cast<const float4*>(&As[k][tm * 4]);
            float4 b4 = *reinterpret_cast<const float4*>(&Bs[k][tn * 4]);
            acc[0][0] = fmaf(a4.x, b4.x, acc[0][0]); acc[0][1] = fmaf(a4.x, b4.y, acc[0][1]);
            acc[0][2] = fmaf(a4.x, b4.z, acc[0][2]); acc[0][3] = fmaf(a4.x, b4.w, acc[0][3]);
            acc[1][0] = fmaf(a4.y, b4.x, acc[1][0]); acc[1][1] = fmaf(a4.y, b4.y, acc[1][1]);
            acc[1][2] = fmaf(a4.y, b4.z, acc[1][2]); acc[1][3] = fmaf(a4.y, b4.w, acc[1][3]);
            acc[2][0] = fmaf(a4.z, b4.x, acc[2][0]); acc[2][1] = fmaf(a4.z, b4.y, acc[2][1]);
            acc[2][2] = fmaf(a4.z, b4.z, acc[2][2]); acc[2][3] = fmaf(a4.z, b4.w, acc[2][3]);
            acc[3][0] = fmaf(a4.w, b4.x, acc[3][0]); acc[3][1] = fmaf(a4.w, b4.y, acc[3][1]);
            acc[3][2] = fmaf(a4.w, b4.z, acc[3][2]); acc[3][3] = fmaf(a4.w, b4.w, acc[3][3]);
        }
    }

    float4 bb = *reinterpret_cast<const float4*>(&bias[n0 + tn * 4]);
    #pragma unroll
    for (int i = 0; i < 4; ++i) {
        int m = m0 + tm * 4 + i;
        float4 o;
        o.x = acc[i][0] + bb.x; o.y = acc[i][1] + bb.y;
        o.z = acc[i][2] + bb.z; o.w = acc[i][3] + bb.w;
        *reinterpret_cast<float4*>(&C[(size_t)m * N + n0 + tn * 4]) = o;
    }
}

// ---------------- host launcher ----------------
extern "C" void kernel_launch(void* const* d_in, const int* in_sizes, int n_in,
                              void* d_out, int out_size, void* d_ws, size_t ws_size,
                              hipStream_t stream) {
    (void)in_sizes; (void)n_in; (void)out_size; (void)ws_size;
    const float* x    = (const float*)d_in[0];
    const float* Wih0 = (const float*)d_in[1];
    const float* Whh0 = (const float*)d_in[2];
    const float* bih0 = (const float*)d_in[3];
    const float* bhh0 = (const float*)d_in[4];
    const float* Wih1 = (const float*)d_in[5];
    const float* Whh1 = (const float*)d_in[6];
    const float* bih1 = (const float*)d_in[7];
    const float* bhh1 = (const float*)d_in[8];
    const float* fcW  = (const float*)d_in[9];
    const float* fcb  = (const float*)d_in[10];

    float* out = (float*)d_out;                       // [B,T,O]
    float* hid = out + (size_t)Bsz * Tt * Osz;        // [L,B,H]

    char* ws = (char*)d_ws;
    const size_t xp_off   = 0;
    const size_t hall_off = xp_off + (size_t)Bsz * Tt * G3 * 4;
    const size_t pbuf_off = hall_off + (size_t)Bsz * Tt * Hsz * 4;   // 2*B*H*8B
    float* xp    = (float*)(ws + xp_off);
    float* hall  = (float*)(ws + hall_off);
    u32x2* pbuf  = (u32x2*)(ws + pbuf_off);

    // layer 0 input projection: xp = x @ Wih0^T + bih0   (M=16384, N=1536, K=256)
    hipLaunchKernelGGL(gemm_nt_bias, dim3(G3 / GN, (Bsz * Tt) / GM), dim3(256), 0, stream,
                       x, Wih0, bih0, xp, Bsz * Tt, G3, Isz);

    // init exchange buffer for layer 0, then recurrence
    hipLaunchKernelGGL(init_pbuf, dim3(64), dim3(256), 0, stream, pbuf, G0_L0);
    hipLaunchKernelGGL(gru_rec, dim3(NBLK), dim3(TPB), 0, stream,
                       xp, Whh0, bhh0, hall, pbuf, hid, G0_L0);

    // layer 1 input projection: xp = hall @ Wih1^T + bih1  (M=16384, N=1536, K=512)
    hipLaunchKernelGGL(gemm_nt_bias, dim3(G3 / GN, (Bsz * Tt) / GM), dim3(256), 0, stream,
                       hall, Wih1, bih1, xp, Bsz * Tt, G3, Hsz);

    // init exchange buffer for layer 1, then recurrence (overwrites hall)
    hipLaunchKernelGGL(init_pbuf, dim3(64), dim3(256), 0, stream, pbuf, G0_L1);
    hipLaunchKernelGGL(gru_rec, dim3(NBLK), dim3(TPB), 0, stream,
                       xp, Whh1, bhh1, hall, pbuf, hid + Bsz * Hsz, G0_L1);

    // FC: out = hall @ fcW^T + fcb  (M=16384, N=128, K=512)
    hipLaunchKernelGGL(gemm_nt_bias, dim3(Osz / GN, (Bsz * Tt) / GM), dim3(256), 0, stream,
                       hall, fcW, fcb, out, Bsz * Tt, Osz, Hsz);
}

// Round 6
// 2312.600 us; speedup vs baseline: 24.1706x; 1.7617x over previous
//
#include <hip/hip_runtime.h>
#include <math.h>

// Problem constants
#define Bsz 32
#define Tt  512
#define Isz 256
#define Hsz 512
#define G3  1536
#define Osz 128

// Recurrence config: 256 blocks = 32 batches x 8 col-groups; 512 threads.
// b = blockIdx&31 so a batch's 8 blocks land on one XCD under round-robin
// (locality bonus only; correctness uses device-coherent sc0sc1 throughout).
#define NBLK 256
#define TPB  512
#define G0_L0 1u
#define G0_L1 4096u

typedef float f4  __attribute__((ext_vector_type(4)));
typedef unsigned int u32;
typedef u32 u32x2 __attribute__((ext_vector_type(2)));

__device__ __forceinline__ float sigf(float x) { return 1.0f / (1.0f + expf(-x)); }

// ---------------- init pbuf: slot0 = (h0=0, gen0), slot1 = invalid ----------------
__global__ void init_pbuf(u32x2* pbuf, u32 gen0) {
    int i = threadIdx.x + blockIdx.x * blockDim.x;
    const int n = Bsz * Hsz;
    for (; i < n; i += gridDim.x * blockDim.x) {
        pbuf[i]     = (u32x2){0u, gen0};   // slot 0: h0 = 0, valid with gen0
        pbuf[n + i] = (u32x2){0u, 0u};     // slot 1: gen invalid
    }
}

// ---------------- persistent GRU recurrence (one layer), batch-split ----------------
// Block (b,p): batch b, output h-cols [p*64, p*64+64). Thread (jl=tid>>3,
// kc=tid&7): col j=p*64+jl, k-range [kc*64, kc*64+64). 192 weight floats per
// thread PINNED in VGPRs via keep-alive asm (compiler must not re-fetch).
// Exchange is per batch via (val,gen) pairs at IC scope (sc0sc1); each thread
// polls exactly one pair per step.
__global__ void __launch_bounds__(TPB, 2) gru_rec(
    const float* __restrict__ xp,    // [B*T, 3H] (includes b_ih)
    const float* __restrict__ Whh,   // [3H, H]
    const float* __restrict__ bhh,   // [3H]
    float* __restrict__ hall,        // [B*T, H]
    u32x2* __restrict__ pbuf,        // [2][B*H] (val,gen)
    float* __restrict__ hid_out,     // [B*H] slice of d_out hidden
    u32 g0)
{
    const int tid = threadIdx.x;
    const int b   = blockIdx.x & 31;        // batch element
    const int p   = blockIdx.x >> 5;        // col-group
    const int jl  = tid >> 3;               // local col 0..63
    const int kc  = tid & 7;                // k-chunk (8 chunks of 64)
    const int j   = p * 64 + jl;            // h-col

    // h of batch b: 8 chunks of 64 floats padded to 68 (conflict-free f4 reads)
    __shared__ float hsh[8 * 68];

    // ---- load weights: rows {g*H+j}, k in [kc*64, +64)  -> 48 f4 = 192 VGPRs ----
    f4 wreg[3][16];
    #pragma unroll
    for (int g = 0; g < 3; ++g) {
        const float* wp = Whh + (size_t)(g * Hsz + j) * Hsz + kc * 64;
        #pragma unroll
        for (int q = 0; q < 16; ++q)
            wreg[g][q] = *reinterpret_cast<const f4*>(wp + q * 4);
    }
    // pin in VGPRs: opaque redefinition -> no rematerialization inside the loop
    #pragma unroll
    for (int g = 0; g < 3; ++g)
        #pragma unroll
        for (int q = 0; q < 16; ++q)
            asm volatile("" : "+v"(wreg[g][q]));

    const float bh0 = bhh[0 * Hsz + j];
    const float bh1 = bhh[1 * Hsz + j];
    const float bh2 = bhh[2 * Hsz + j];

    for (int t = 0; t < Tt; ++t) {
        const u32 rg = g0 + (u32)t;
        const u32 wg = rg + 1u;
        const u32x2* src = pbuf + (size_t)(t & 1) * (Bsz * Hsz) + b * Hsz;
        u32x2*       dst = pbuf + (size_t)((t + 1) & 1) * (Bsz * Hsz) + b * Hsz;

        // xp for owner lanes (plain cached loads; issued before poll)
        float xr = 0.f, xz = 0.f, xn = 0.f;
        if (kc == 0) {
            const float* pp = xp + (size_t)(b * Tt + t) * G3;
            xr = pp[j];
            xz = pp[Hsz + j];
            xn = pp[2 * Hsz + j];
        }

        // ---- poll own pair (1 per thread, per-wave convergence), stage to LDS ----
        {
            const u32x2* sp = src + tid;
            for (;;) {
                u32x2 pr;
                asm volatile("global_load_dwordx2 %0, %1, off sc0 sc1\n\t"
                             "s_waitcnt vmcnt(0)"
                             : "=&v"(pr) : "v"(sp) : "memory");
                if (__all(pr[1] == rg)) {
                    hsh[(tid >> 6) * 68 + (tid & 63)] = __uint_as_float(pr[0]);
                    break;
                }
                __builtin_amdgcn_s_sleep(1);
            }
        }
        __syncthreads();

        // ---- compute: 3 gate partials over k in [kc*64, +64) ----
        float a0 = 0.f, a1 = 0.f, a2 = 0.f;
        {
            const f4* hp = reinterpret_cast<const f4*>(hsh) + kc * 17;  // 68/4
            #pragma unroll
            for (int q = 0; q < 16; ++q) {
                f4 hv4 = hp[q];
                a0 = fmaf(wreg[0][q][0], hv4[0], a0);
                a0 = fmaf(wreg[0][q][1], hv4[1], a0);
                a0 = fmaf(wreg[0][q][2], hv4[2], a0);
                a0 = fmaf(wreg[0][q][3], hv4[3], a0);
                a1 = fmaf(wreg[1][q][0], hv4[0], a1);
                a1 = fmaf(wreg[1][q][1], hv4[1], a1);
                a1 = fmaf(wreg[1][q][2], hv4[2], a1);
                a1 = fmaf(wreg[1][q][3], hv4[3], a1);
                a2 = fmaf(wreg[2][q][0], hv4[0], a2);
                a2 = fmaf(wreg[2][q][1], hv4[1], a2);
                a2 = fmaf(wreg[2][q][2], hv4[2], a2);
                a2 = fmaf(wreg[2][q][3], hv4[3], a2);
            }
        }

        // reduce across the 8 kc lanes (low 3 lane bits)
        #pragma unroll
        for (int off = 1; off < 8; off <<= 1) {
            a0 += __shfl_xor(a0, off, 64);
            a1 += __shfl_xor(a1, off, 64);
            a2 += __shfl_xor(a2, off, 64);
        }

        if (kc == 0) {
            float rr = sigf(xr + a0 + bh0);
            float zz = sigf(xz + a1 + bh1);
            float nn = tanhf(xn + rr * (a2 + bh2));
            float ho = hsh[(j >> 6) * 68 + (j & 63)];
            float hv = (1.0f - zz) * nn + zz * ho;
            u32x2 pk = (u32x2){__float_as_uint(hv), wg};
            asm volatile("global_store_dwordx2 %0, %1, off sc0 sc1"
                         :: "v"(dst + j), "v"(pk) : "memory");
            hall[(size_t)(b * Tt + t) * Hsz + j] = hv;       // plain
            if (t == Tt - 1) hid_out[b * Hsz + j] = hv;
        }

        __syncthreads();   // protect hsh before next step's staging
    }
}

// ---------------- fp32 GEMM: C[M,N] = A[M,K] * W[N,K]^T + bias[N] ----------------
#define GM 64
#define GN 64
#define GK 16
__global__ void __launch_bounds__(256) gemm_nt_bias(
    const float* __restrict__ A, const float* __restrict__ W,
    const float* __restrict__ bias, float* __restrict__ C,
    int M, int N, int K)
{
    __shared__ float As[GK][GM];
    __shared__ float Bs[GK][GN];
    const int tid = threadIdx.x;
    const int n0 = blockIdx.x * GN;
    const int m0 = blockIdx.y * GM;
    const int tn = tid & 15;
    const int tm = tid >> 4;
    const int lrow = tid >> 2;   // 0..63
    const int lkq  = tid & 3;    // 0..3

    float acc[4][4];
    #pragma unroll
    for (int i = 0; i < 4; ++i)
        #pragma unroll
        for (int jj = 0; jj < 4; ++jj) acc[i][jj] = 0.0f;

    for (int k0 = 0; k0 < K; k0 += GK) {
        float4 av = *reinterpret_cast<const float4*>(&A[(size_t)(m0 + lrow) * K + k0 + lkq * 4]);
        float4 wv = *reinterpret_cast<const float4*>(&W[(size_t)(n0 + lrow) * K + k0 + lkq * 4]);
        __syncthreads();
        As[lkq * 4 + 0][lrow] = av.x; As[lkq * 4 + 1][lrow] = av.y;
        As[lkq * 4 + 2][lrow] = av.z; As[lkq * 4 + 3][lrow] = av.w;
        Bs[lkq * 4 + 0][lrow] = wv.x; Bs[lkq * 4 + 1][lrow] = wv.y;
        Bs[lkq * 4 + 2][lrow] = wv.z; Bs[lkq * 4 + 3][lrow] = wv.w;
        __syncthreads();
        #pragma unroll
        for (int k = 0; k < GK; ++k) {
            float4 a4 = *reinterpret_cast<const float4*>(&As[k][tm * 4]);
            float4 b4 = *reinterpret_cast<const float4*>(&Bs[k][tn * 4]);
            acc[0][0] = fmaf(a4.x, b4.x, acc[0][0]); acc[0][1] = fmaf(a4.x, b4.y, acc[0][1]);
            acc[0][2] = fmaf(a4.x, b4.z, acc[0][2]); acc[0][3] = fmaf(a4.x, b4.w, acc[0][3]);
            acc[1][0] = fmaf(a4.y, b4.x, acc[1][0]); acc[1][1] = fmaf(a4.y, b4.y, acc[1][1]);
            acc[1][2] = fmaf(a4.y, b4.z, acc[1][2]); acc[1][3] = fmaf(a4.y, b4.w, acc[1][3]);
            acc[2][0] = fmaf(a4.z, b4.x, acc[2][0]); acc[2][1] = fmaf(a4.z, b4.y, acc[2][1]);
            acc[2][2] = fmaf(a4.z, b4.z, acc[2][2]); acc[2][3] = fmaf(a4.z, b4.w, acc[2][3]);
            acc[3][0] = fmaf(a4.w, b4.x, acc[3][0]); acc[3][1] = fmaf(a4.w, b4.y, acc[3][1]);
            acc[3][2] = fmaf(a4.w, b4.z, acc[3][2]); acc[3][3] = fmaf(a4.w, b4.w, acc[3][3]);
        }
    }

    float4 bb = *reinterpret_cast<const float4*>(&bias[n0 + tn * 4]);
    #pragma unroll
    for (int i = 0; i < 4; ++i) {
        int m = m0 + tm * 4 + i;
        float4 o;
        o.x = acc[i][0] + bb.x; o.y = acc[i][1] + bb.y;
        o.z = acc[i][2] + bb.z; o.w = acc[i][3] + bb.w;
        *reinterpret_cast<float4*>(&C[(size_t)m * N + n0 + tn * 4]) = o;
    }
}

// ---------------- host launcher ----------------
extern "C" void kernel_launch(void* const* d_in, const int* in_sizes, int n_in,
                              void* d_out, int out_size, void* d_ws, size_t ws_size,
                              hipStream_t stream) {
    (void)in_sizes; (void)n_in; (void)out_size; (void)ws_size;
    const float* x    = (const float*)d_in[0];
    const float* Wih0 = (const float*)d_in[1];
    const float* Whh0 = (const float*)d_in[2];
    const float* bih0 = (const float*)d_in[3];
    const float* bhh0 = (const float*)d_in[4];
    const float* Wih1 = (const float*)d_in[5];
    const float* Whh1 = (const float*)d_in[6];
    const float* bih1 = (const float*)d_in[7];
    const float* bhh1 = (const float*)d_in[8];
    const float* fcW  = (const float*)d_in[9];
    const float* fcb  = (const float*)d_in[10];

    float* out = (float*)d_out;                       // [B,T,O]
    float* hid = out + (size_t)Bsz * Tt * Osz;        // [L,B,H]

    char* ws = (char*)d_ws;
    const size_t xp_off   = 0;
    const size_t hall_off = xp_off + (size_t)Bsz * Tt * G3 * 4;
    const size_t pbuf_off = hall_off + (size_t)Bsz * Tt * Hsz * 4;   // 2*B*H*8B
    float* xp    = (float*)(ws + xp_off);
    float* hall  = (float*)(ws + hall_off);
    u32x2* pbuf  = (u32x2*)(ws + pbuf_off);

    // layer 0 input projection: xp = x @ Wih0^T + bih0   (M=16384, N=1536, K=256)
    hipLaunchKernelGGL(gemm_nt_bias, dim3(G3 / GN, (Bsz * Tt) / GM), dim3(256), 0, stream,
                       x, Wih0, bih0, xp, Bsz * Tt, G3, Isz);

    // init exchange buffer for layer 0, then recurrence
    hipLaunchKernelGGL(init_pbuf, dim3(64), dim3(256), 0, stream, pbuf, G0_L0);
    hipLaunchKernelGGL(gru_rec, dim3(NBLK), dim3(TPB), 0, stream,
                       xp, Whh0, bhh0, hall, pbuf, hid, G0_L0);

    // layer 1 input projection: xp = hall @ Wih1^T + bih1  (M=16384, N=1536, K=512)
    hipLaunchKernelGGL(gemm_nt_bias, dim3(G3 / GN, (Bsz * Tt) / GM), dim3(256), 0, stream,
                       hall, Wih1, bih1, xp, Bsz * Tt, G3, Hsz);

    // init exchange buffer for layer 1, then recurrence (overwrites hall)
    hipLaunchKernelGGL(init_pbuf, dim3(64), dim3(256), 0, stream, pbuf, G0_L1);
    hipLaunchKernelGGL(gru_rec, dim3(NBLK), dim3(TPB), 0, stream,
                       xp, Whh1, bhh1, hall, pbuf, hid + Bsz * Hsz, G0_L1);

    // FC: out = hall @ fcW^T + fcb  (M=16384, N=128, K=512)
    hipLaunchKernelGGL(gemm_nt_bias, dim3(Osz / GN, (Bsz * Tt) / GM), dim3(256), 0, stream,
                       hall, fcW, fcb, out, Bsz * Tt, Osz, Hsz);
}